// Round 13
// baseline (271.923 us; speedup 1.0000x reference)
//
#include <hip/hip_runtime.h>
#include <hip/hip_bf16.h>

typedef __bf16 bf16x8 __attribute__((ext_vector_type(8)));
typedef __bf16 bf16x4 __attribute__((ext_vector_type(4)));
typedef float  f32x4  __attribute__((ext_vector_type(4)));

#define MFMA16(A,B,C) __builtin_amdgcn_mfma_f32_16x16x32_bf16((A),(B),(C),0,0,0)

constexpr int NB = 8, NN = 8192, KK = 16;
constexpr int XS = 72;            // LDS row stride (elements): 144B; conflicts measured negligible (1.3us)
constexpr size_t WS_NEEDED = 78848;

// Permuted k-order everywhere (exact): channel c = cb*16+u <-> slot p = u*4+cb.
// ws layout: w3f 32768 @0 | w4f 32768 @32768 | w2f 8192 @65536 | w1f 4096 @73728 | c3f 1024 @77824

__global__ void prep_kernel(const float* __restrict__ W1, const float* __restrict__ b1,
                            const float* __restrict__ g1, const float* __restrict__ bt1,
                            const float* __restrict__ W2, const float* __restrict__ W3,
                            const float* __restrict__ b3, const float* __restrict__ g3,
                            const float* __restrict__ bt3, const float* __restrict__ W4,
                            unsigned char* __restrict__ ws)
{
    __bf16* w3f = (__bf16*)(ws);
    __bf16* w4f = (__bf16*)(ws + 32768);
    __bf16* w2f = (__bf16*)(ws + 65536);
    __bf16* w1f = (__bf16*)(ws + 73728);
    float*  c3f = (float*)(ws + 77824);

    const float inv = 1.0f / sqrtf(1.0f + 1e-3f);   // BN with init moving stats
    int t = blockIdx.x * 256 + threadIdx.x;

    if (t < 16384) {                    // w3f
        int i = t & 7, lane = (t >> 3) & 63, r = t >> 9;
        int ks = r & 1, nb = r >> 1;
        int p = ks * 32 + (lane >> 4) * 8 + i;
        int c = (p & 3) * 16 + (p >> 2);
        int n = nb * 16 + (lane & 15);
        w3f[t] = (__bf16)(W3[c * 256 + n] * (g3[n] * inv));
    } else if (t < 32768) {             // w4f
        int u = t - 16384;
        int i = u & 7, lane = (u >> 3) & 63, r = u >> 9;
        int kb = r & 7, nb = r >> 3;
        int q = (kb & 1) * 32 + (lane >> 4) * 8 + i;
        int c = (kb >> 1) * 64 + (q & 3) * 16 + (q >> 2);
        int n = nb * 16 + (lane & 15);
        w4f[u] = (__bf16)(W4[c * 64 + n] * 0.125f);
    } else if (t < 36864) {             // w2f
        int u = t - 32768;
        int i = u & 7, lane = (u >> 3) & 63, r = u >> 9;
        int ks = r & 1, nb = r >> 1;
        int p = ks * 32 + (lane >> 4) * 8 + i;
        int c = (p & 3) * 16 + (p >> 2);
        int n = nb * 16 + (lane & 15);
        w2f[u] = (__bf16)(W2[c * 64 + n]);
    } else if (t < 38912) {             // w1f (k=3 = BN-folded bias row; A-side supplies 1.0)
        int u = t - 36864;
        int i = u & 7, lane = (u >> 3) & 63, nb = u >> 9;
        int kk = (lane >> 4) * 8 + i;
        int n = nb * 16 + (lane & 15);
        float v = 0.f;
        if (kk < 3)       v = W1[kk * 64 + n] * (g1[n] * inv);
        else if (kk == 3) v = b1[n] * (g1[n] * inv) + bt1[n];
        w1f[u] = (__bf16)v;
    } else if (t < 39168) {             // c3f
        int n = t - 38912;
        c3f[n] = b3[n] * (g3[n] * inv) + bt3[n];
    }
}

// One wave = 2 points. No barriers. Gathers prefetched ahead of the MFMA chain.
// Biases+query folded into MFMA C-in. cc loop: unrolled, ping-pong LDS bounce AND
// software-pipelined {G1(cc); G2(cc-1); epi(cc)} so every epi-write -> G2-read pair
// is separated by a 16-MFMA cluster (DS pipe is in-order per wave; r12's immediate
// write->read turnaround stalled ~70-100cy x4/wave).
__global__ __launch_bounds__(256, 2) void fused_kernel(
    const float* __restrict__ key, const float* __restrict__ query,
    const float* __restrict__ value, const float* __restrict__ pos,
    const int* __restrict__ idx, const float* __restrict__ b2,
    const float* __restrict__ b4, const unsigned char* __restrict__ ws,
    float* __restrict__ out)
{
    const __bf16* w3f = (const __bf16*)(ws);
    const __bf16* w4f = (const __bf16*)(ws + 32768);
    const __bf16* w2f = (const __bf16*)(ws + 65536);
    const __bf16* w1f = (const __bf16*)(ws + 73728);
    const float*  c3f = (const float*)(ws + 77824);

    const f32x4 ZERO4 = {0.f, 0.f, 0.f, 0.f};

    __shared__ __attribute__((aligned(16))) __bf16 sX [4][32 * XS];  // h, X, then ping-pong buf
    __shared__ __attribute__((aligned(16))) __bf16 sA1[4][32 * XS];  // GEMM1 chunk bounce (pong)

    const int wv   = threadIdx.x >> 6;
    const int lane = threadIdx.x & 63;
    const int lg   = lane >> 4;      // 16-lane group 0..3
    const int ln   = lane & 15;

    const int ptbase = blockIdx.x * 8 + wv * 2;  // global point of rb=0
    const int b  = ptbase >> 13;                 // / 8192
    const int n0 = ptbase & 8191;

    __bf16* X  = sX[wv];
    __bf16* A1 = sA1[wv];

    // ---------- Prefetch wave-local inputs (issue ASAP; consumed much later)
    float qv[2][4], vvv[2][4], b4v[4];
    #pragma unroll
    for (int rb = 0; rb < 2; ++rb)
        #pragma unroll
        for (int cb = 0; cb < 4; ++cb) {
            qv[rb][cb]  = query[(b * NN + n0 + rb) * 64 + cb * 16 + ln];
            vvv[rb][cb] = value[(b * NN + n0 + rb) * 64 + cb * 16 + ln];
        }
    #pragma unroll
    for (int nb = 0; nb < 4; ++nb) b4v[nb] = b4[nb * 16 + ln] * 0.125f;
    float b2v[4];
    #pragma unroll
    for (int cb = 0; cb < 4; ++cb) b2v[cb] = b2[cb * 16 + ln];

    // idx + pos gather (lane<32 covers the 32 rows; row r of point p held by lane p*16+(r&15))
    int   jl = 0;
    float prx = 0.f, pry = 0.f, prz = 0.f;
    if (lane < 32) {
        int p = lane >> 4, k = lane & 15;
        int n = n0 + p;
        jl = idx[(b * NN + n) * KK + k];
        int pb = (b * NN + n) * 3, jb = (b * NN + jl) * 3;
        prx = pos[pb + 0] - pos[jb + 0];
        pry = pos[pb + 1] - pos[jb + 1];
        prz = pos[pb + 2] - pos[jb + 2];
    }

    // key gather prefetch: j via shfl (src lane rb*16+lg*4+jj); ~200cy L2 latency hides
    // under Phase A+B MFMAs.
    float kreg[2][4][4];
    #pragma unroll
    for (int rb = 0; rb < 2; ++rb)
        #pragma unroll
        for (int jj = 0; jj < 4; ++jj) {
            int j = __shfl(jl, rb * 16 + lg * 4 + jj, 64);
            int jb = (b * NN + j) * 64;
            #pragma unroll
            for (int cb = 0; cb < 4; ++cb)
                kreg[rb][jj][cb] = key[jb + cb * 16 + ln];
        }

    // ---------- Phase A: h = relu(PR @ W1f) via MFMA (bias at k=3, A supplies 1.0)
    bf16x8 af[2];
    #pragma unroll
    for (int rb = 0; rb < 2; ++rb) {
        float ax = __shfl(prx, rb * 16 + ln, 64);
        float ay = __shfl(pry, rb * 16 + ln, 64);
        float az = __shfl(prz, rb * 16 + ln, 64);
        bf16x8 a;
        #pragma unroll
        for (int i = 0; i < 8; ++i) a[i] = (__bf16)0.0f;
        if (lg == 0) {
            a[0] = (__bf16)ax; a[1] = (__bf16)ay; a[2] = (__bf16)az;
            a[3] = (__bf16)1.0f;
        }
        af[rb] = a;
    }
    f32x4 pa[2][4];
    #pragma unroll
    for (int nb = 0; nb < 4; ++nb) {
        bf16x8 wf = *(const bf16x8*)(w1f + (size_t)(nb * 64 + lane) * 8);
        pa[0][nb] = MFMA16(af[0], wf, ZERO4);
        pa[1][nb] = MFMA16(af[1], wf, ZERO4);
    }
    // h epilogue: relu -> packed b64 at permuted slots (slot p = ln*4 + nb)
    #pragma unroll
    for (int rb = 0; rb < 2; ++rb)
        #pragma unroll
        for (int jj = 0; jj < 4; ++jj) {
            int row = rb * 16 + lg * 4 + jj;
            bf16x4 hv;
            #pragma unroll
            for (int nb = 0; nb < 4; ++nb) hv[nb] = (__bf16)fmaxf(pa[rb][nb][jj], 0.f);
            *(bf16x4*)&X[row * XS + ln * 4] = hv;
        }

    // ---------- Phase B: pacc = h @ W2f + (b2 + q)   (pacc = posem + q, C-in folded)
    bf16x8 hf[2][2];
    #pragma unroll
    for (int rb = 0; rb < 2; ++rb)
        #pragma unroll
        for (int ks = 0; ks < 2; ++ks)
            hf[rb][ks] = *(const bf16x8*)&X[(rb * 16 + ln) * XS + ks * 32 + lg * 8];
    f32x4 pacc[2][4];
    #pragma unroll
    for (int rb = 0; rb < 2; ++rb)
        #pragma unroll
        for (int cb = 0; cb < 4; ++cb) {
            float c0s = b2v[cb] + qv[rb][cb];
            f32x4 c0 = {c0s, c0s, c0s, c0s};
            pacc[rb][cb] = c0;
        }
    // vvv becomes (v - q); qv dead after this point. Phase F uses vvv + pacc = v + posem.
    #pragma unroll
    for (int rb = 0; rb < 2; ++rb)
        #pragma unroll
        for (int cb = 0; cb < 4; ++cb) vvv[rb][cb] -= qv[rb][cb];
    #pragma unroll
    for (int cb = 0; cb < 4; ++cb)
        #pragma unroll
        for (int ks = 0; ks < 2; ++ks) {
            bf16x8 wf = *(const bf16x8*)(w2f + (size_t)((cb * 2 + ks) * 64 + lane) * 8);
            pacc[0][cb] = MFMA16(hf[0][ks], wf, pacc[0][cb]);
            pacc[1][cb] = MFMA16(hf[1][ks], wf, pacc[1][cb]);
        }

    // X = pacc - key (= q - key + posem), packed write (C-layout: col=ln, row=lg*4+jj)
    #pragma unroll
    for (int rb = 0; rb < 2; ++rb)
        #pragma unroll
        for (int jj = 0; jj < 4; ++jj) {
            int row = rb * 16 + lg * 4 + jj;
            bf16x4 xv;
            #pragma unroll
            for (int cb = 0; cb < 4; ++cb)
                xv[cb] = (__bf16)(pacc[rb][cb][jj] - kreg[rb][jj][cb]);
            *(bf16x4*)&X[row * XS + ln * 4] = xv;
        }

    // ---------- Phase D (pipelined): per cc: G1(cc) MFMAs -> G2(cc-1) -> epi(cc).
    // Ping-pong BUF (X dead region <-> A1) gives WAR freedom; the G2(cc-1) reads hit a
    // buffer whose writes drained one full iteration ago.
    bf16x8 xf[2][2];
    #pragma unroll
    for (int rb = 0; rb < 2; ++rb)
        #pragma unroll
        for (int ks = 0; ks < 2; ++ks)
            xf[rb][ks] = *(const bf16x8*)&X[(rb * 16 + ln) * XS + ks * 32 + lg * 8];
    f32x4 acc2[2][4];
    #pragma unroll
    for (int rb = 0; rb < 2; ++rb)
        #pragma unroll
        for (int nb = 0; nb < 4; ++nb) {
            f32x4 c0 = {b4v[nb], b4v[nb], b4v[nb], b4v[nb]};
            acc2[rb][nb] = c0;   // b4 folded into GEMM2 C-in
        }

    #pragma unroll
    for (int cc = 0; cc < 4; ++cc) {
        __bf16* BUF = (cc & 1) ? X : A1;   // constant after unroll
        // ---- G1(cc): 16 MFMAs into g1a (c3 folded into C-in)
        f32x4 g1a[2][4];
        #pragma unroll
        for (int cb = 0; cb < 4; ++cb) {
            float c3v = c3f[(cc * 4 + cb) * 16 + ln];
            f32x4 c0 = {c3v, c3v, c3v, c3v};
            g1a[0][cb] = c0;
            g1a[1][cb] = c0;
        }
        __builtin_amdgcn_s_setprio(1);
        #pragma unroll
        for (int cb = 0; cb < 4; ++cb) {
            int nb = cc * 4 + cb;
            #pragma unroll
            for (int ks = 0; ks < 2; ++ks) {
                bf16x8 wf = *(const bf16x8*)(w3f + (size_t)((nb * 2 + ks) * 64 + lane) * 8);
                g1a[0][cb] = MFMA16(xf[0][ks], wf, g1a[0][cb]);
                g1a[1][cb] = MFMA16(xf[1][ks], wf, g1a[1][cb]);
            }
        }
        __builtin_amdgcn_s_setprio(0);
        // ---- G2(cc-1): read prev buffer (drained during G1 above), 16 MFMAs into acc2
        if (cc >= 1) {
            __bf16* PBUF = ((cc - 1) & 1) ? X : A1;
            #pragma unroll
            for (int kb2 = 0; kb2 < 2; ++kb2) {
                bf16x8 a1f[2];
                #pragma unroll
                for (int rb = 0; rb < 2; ++rb)
                    a1f[rb] = *(const bf16x8*)&PBUF[(rb * 16 + ln) * XS + kb2 * 32 + lg * 8];
                __builtin_amdgcn_s_setprio(1);
                #pragma unroll
                for (int nb = 0; nb < 4; ++nb) {
                    bf16x8 wf = *(const bf16x8*)(w4f + (size_t)((nb * 8 + (cc - 1) * 2 + kb2) * 64 + lane) * 8);
                    acc2[0][nb] = MFMA16(a1f[0], wf, acc2[0][nb]);
                    acc2[1][nb] = MFMA16(a1f[1], wf, acc2[1][nb]);
                }
                __builtin_amdgcn_s_setprio(0);
            }
        }
        // ---- epi(cc): relu -> packed b64 into BUF (read one iteration later)
        #pragma unroll
        for (int rb = 0; rb < 2; ++rb)
            #pragma unroll
            for (int jj = 0; jj < 4; ++jj) {
                int row = rb * 16 + lg * 4 + jj;
                bf16x4 av;
                #pragma unroll
                for (int cb = 0; cb < 4; ++cb)
                    av[cb] = (__bf16)fmaxf(g1a[rb][cb][jj], 0.f);
                *(bf16x4*)&BUF[row * XS + ln * 4] = av;
            }
    }
    // ---- tail: G2(3) from BUF(3) = X
    #pragma unroll
    for (int kb2 = 0; kb2 < 2; ++kb2) {
        bf16x8 a1f[2];
        #pragma unroll
        for (int rb = 0; rb < 2; ++rb)
            a1f[rb] = *(const bf16x8*)&X[(rb * 16 + ln) * XS + kb2 * 32 + lg * 8];
        __builtin_amdgcn_s_setprio(1);
        #pragma unroll
        for (int nb = 0; nb < 4; ++nb) {
            bf16x8 wf = *(const bf16x8*)(w4f + (size_t)((nb * 8 + 3 * 2 + kb2) * 64 + lane) * 8);
            acc2[0][nb] = MFMA16(a1f[0], wf, acc2[0][nb]);
            acc2[1][nb] = MFMA16(a1f[1], wf, acc2[1][nb]);
        }
        __builtin_amdgcn_s_setprio(0);
    }

    // ---------- Phase F: channel softmax (no max-sub: logits O(1), f32-exp exact ratios)
    #pragma unroll
    for (int rb = 0; rb < 2; ++rb) {
        const int nrow = n0 + rb;
        float res[4] = {0.f, 0.f, 0.f, 0.f};
        #pragma unroll
        for (int jj = 0; jj < 4; ++jj) {   // each jj = one neighbor row per lane group
            float e0 = __expf(acc2[rb][0][jj]);
            float e1 = __expf(acc2[rb][1][jj]);
            float e2 = __expf(acc2[rb][2][jj]);
            float e3 = __expf(acc2[rb][3][jj]);
            float s = (e0 + e1) + (e2 + e3);
            #pragma unroll
            for (int d = 1; d < 16; d <<= 1) s += __shfl_xor(s, d, 64);
            float inv = 1.0f / s;
            res[0] = fmaf(e0 * inv, vvv[rb][0] + pacc[rb][0][jj], res[0]);
            res[1] = fmaf(e1 * inv, vvv[rb][1] + pacc[rb][1][jj], res[1]);
            res[2] = fmaf(e2 * inv, vvv[rb][2] + pacc[rb][2][jj], res[2]);
            res[3] = fmaf(e3 * inv, vvv[rb][3] + pacc[rb][3][jj], res[3]);
        }
        #pragma unroll
        for (int nb = 0; nb < 4; ++nb) {   // sum over the 4 lane groups (16 neighbors total)
            res[nb] += __shfl_xor(res[nb], 16, 64);
            res[nb] += __shfl_xor(res[nb], 32, 64);
        }
        float o = (lg == 0) ? res[0] : (lg == 1) ? res[1] : (lg == 2) ? res[2] : res[3];
        out[(b * NN + nrow) * 64 + lane] = o;
    }
}

extern "C" void kernel_launch(void* const* d_in, const int* in_sizes, int n_in,
                              void* d_out, int out_size, void* d_ws, size_t ws_size,
                              hipStream_t stream) {
    const float* key   = (const float*)d_in[0];
    const float* query = (const float*)d_in[1];
    const float* value = (const float*)d_in[2];
    const float* pos   = (const float*)d_in[3];
    const int*   idx   = (const int*)d_in[4];
    const float* W1    = (const float*)d_in[5];
    const float* b1    = (const float*)d_in[6];
    const float* g1    = (const float*)d_in[7];
    const float* bt1   = (const float*)d_in[8];
    const float* W2    = (const float*)d_in[9];
    const float* b2    = (const float*)d_in[10];
    const float* W3    = (const float*)d_in[11];
    const float* b3    = (const float*)d_in[12];
    const float* g3    = (const float*)d_in[13];
    const float* bt3   = (const float*)d_in[14];
    const float* W4    = (const float*)d_in[15];
    const float* b4    = (const float*)d_in[16];
    unsigned char* ws  = (unsigned char*)d_ws;
    float* out = (float*)d_out;

    if (ws_size < WS_NEEDED) return;   // fail cleanly instead of corrupting device memory

    hipLaunchKernelGGL(prep_kernel, dim3(153), dim3(256), 0, stream,
                       W1, b1, g1, bt1, W2, W3, b3, g3, bt3, W4, ws);
    hipLaunchKernelGGL(fused_kernel, dim3(8192), dim3(256), 0, stream,
                       key, query, value, pos, idx, b2, b4, ws, out);
}